// Round 9
// baseline (246.503 us; speedup 1.0000x reference)
//
#include <hip/hip_runtime.h>
#include <hip/hip_bf16.h>

typedef __hip_bfloat16 bf16;
typedef unsigned short ushort;
typedef unsigned char uchar;
typedef long i64;   // 64-bit on amdgcn
typedef __attribute__((ext_vector_type(8))) short bf16x8;
typedef __attribute__((ext_vector_type(4))) float f32x4;

#define B_ 8
#define T_ 1024
#define D_ 1024
#define N_ 256
#define L_ 768
#define H_ 16
#define HD_ 64
#define TE_ 2048

__device__ __forceinline__ void gld16(const void* g, void* l) {
    __builtin_amdgcn_global_load_lds((const __attribute__((address_space(1))) void*)g,
                                     (__attribute__((address_space(3))) void*)l,
                                     16, 0, 0);
}

__device__ __forceinline__ float bitf(unsigned u) { return __uint_as_float(u); }

// pack 4 f32 -> 4 fp8 e4m3 bytes (OCP on gfx950)
__device__ __forceinline__ int pk4_fp8(float a, float b, float c, float d) {
    int p = __builtin_amdgcn_cvt_pk_fp8_f32(a, b, 0, false);
    p = __builtin_amdgcn_cvt_pk_fp8_f32(c, d, p, true);
    return p;
}
__device__ __forceinline__ uchar pk1_fp8(float a) {
    int p = __builtin_amdgcn_cvt_pk_fp8_f32(a, a, 0, false);
    return (uchar)(p & 0xff);
}

// ===== prep: LN(x)+LN(xf)->fp8 [0,10240) | tcvt4->fp8 [10240,11136) | emb1 [11136,11392)
__global__ __launch_bounds__(256) void prep_kernel(
        const float* __restrict__ x, const float* __restrict__ xf,
        const float* __restrict__ g1, const float* __restrict__ b1,
        const float* __restrict__ g2, const float* __restrict__ b2,
        const float* __restrict__ Wq, const float* __restrict__ Wk,
        const float* __restrict__ Wv, const float* __restrict__ Wo,
        const float* __restrict__ emb, const float* __restrict__ Wemb,
        uchar* __restrict__ xn8, uchar* __restrict__ xfn8,
        uchar* __restrict__ wq8, uchar* __restrict__ wk8,
        uchar* __restrict__ wv8, uchar* __restrict__ wo8,
        float* __restrict__ part) {
    __shared__ __align__(16) char smem[16384];
    int bid = blockIdx.x;
    int tid = threadIdx.x;
    if (bid < 10240) {
        // LayerNorm, 4 cols/thread, fp8 out
        const float *rp, *g, *bb; uchar* op; int cols;
        if (bid < B_ * T_) {
            rp = x + (size_t)bid * D_; g = g1; bb = b1; op = xn8 + (size_t)bid * D_; cols = D_;
        } else {
            int r = bid - B_ * T_;
            rp = xf + (size_t)r * L_; g = g2; bb = b2; op = xfn8 + (size_t)r * L_; cols = L_;
        }
        float* ps  = (float*)smem;
        float* ps2 = ps + 4;
        float* st  = ps + 8;
        bool act = tid * 4 < cols;
        float4 v = act ? *(const float4*)&rp[tid * 4] : make_float4(0.f, 0.f, 0.f, 0.f);
        float s = v.x + v.y + v.z + v.w;
        float s2 = v.x * v.x + v.y * v.y + v.z * v.z + v.w * v.w;
        for (int off = 32; off; off >>= 1) {
            s  += __shfl_down(s,  off, 64);
            s2 += __shfl_down(s2, off, 64);
        }
        int wid = tid >> 6, lid = tid & 63;
        if (lid == 0) { ps[wid] = s; ps2[wid] = s2; }
        __syncthreads();
        if (tid == 0) {
            float t = ps[0] + ps[1] + ps[2] + ps[3];
            float t2 = ps2[0] + ps2[1] + ps2[2] + ps2[3];
            float m = t / cols;
            float var = t2 / cols - m * m;
            st[0] = m; st[1] = rsqrtf(var + 1e-5f);
        }
        __syncthreads();
        if (!act) return;
        float mu = st[0], rstd = st[1];
        float4 gv = *(const float4*)&g[tid * 4];
        float4 bv = *(const float4*)&bb[tid * 4];
        float o0 = (v.x - mu) * rstd * gv.x + bv.x;
        float o1 = (v.y - mu) * rstd * gv.y + bv.y;
        float o2 = (v.z - mu) * rstd * gv.z + bv.z;
        float o3 = (v.w - mu) * rstd * gv.w + bv.w;
        *(int*)&op[tid * 4] = pk4_fp8(o0, o1, o2, o3);
    } else if (bid < 11136) {
        // weight transpose + f32->fp8: W(KxNc) -> Wt(NcxK)
        uchar (*t)[65] = (uchar(*)[65])smem;
        int id = bid - 10240;
        int xb = id & 15, y = id >> 4;
        const float* W; uchar* Wt; int K, ky;
        if (y < 16)      { W = Wq; Wt = wq8; K = 1024; ky = y; }
        else if (y < 28) { W = Wk; Wt = wk8; K = 768;  ky = y - 16; }
        else if (y < 40) { W = Wv; Wt = wv8; K = 768;  ky = y - 28; }
        else             { W = Wo; Wt = wo8; K = 1024; ky = y - 40; }
        int k0 = ky * 64, n0 = xb * 64;
#pragma unroll
        for (int i = 0; i < 16; i++) {
            int e = tid + i * 256;
            int r = e >> 6, c = e & 63;
            t[r][c] = pk1_fp8(W[(size_t)(k0 + r) * D_ + n0 + c]);
        }
        __syncthreads();
#pragma unroll
        for (int i = 0; i < 4; i++) {
            int e = tid + i * 256;          // 1024 writes of 4B
            int r = e >> 4, cg = (e & 15) * 4;
            unsigned u = (unsigned)t[cg][r] | ((unsigned)t[cg + 1][r] << 8)
                       | ((unsigned)t[cg + 2][r] << 16) | ((unsigned)t[cg + 3][r] << 24);
            *(unsigned*)&Wt[(size_t)(n0 + r) * K + k0 + cg] = u;
        }
    } else {
        // emb1: silu(emb) @ Wemb partial dots
        float* se  = (float*)smem;
        float* red = (float*)(smem + 8192);
        int id = bid - 11136;
        int j0 = (id & 31) * 64;
        int ks = id >> 5;
        int tx = tid & 15, ty = tid >> 4;
        int w = tid >> 6, lane = tid & 63;
#pragma unroll
        for (int b = 0; b < 8; b++) {
            float xv = emb[b * TE_ + ks * 256 + tid];
            se[b * 256 + tid] = xv / (1.f + __expf(-xv));
        }
        __syncthreads();
        float acc[8][4] = {};
#pragma unroll 4
        for (int i = 0; i < 16; i++) {
            int e = ty + 16 * i;
            float4 wv = *(const float4*)&Wemb[(size_t)(ks * 256 + e) * 2048 + j0 + tx * 4];
#pragma unroll
            for (int b = 0; b < 8; b++) {
                float s = se[b * 256 + e];
                acc[b][0] += s * wv.x; acc[b][1] += s * wv.y;
                acc[b][2] += s * wv.z; acc[b][3] += s * wv.w;
            }
        }
#pragma unroll
        for (int b = 0; b < 8; b++)
#pragma unroll
            for (int m = 0; m < 4; m++) {
                float v = acc[b][m];
                v += __shfl_down(v, 32, 64);
                v += __shfl_down(v, 16, 64);
                if (lane < 16) red[(w * 8 + b) * 64 + lane * 4 + m] = v;
            }
        __syncthreads();
        for (int o = tid; o < 512; o += 256) {
            int b = o >> 6, jl = o & 63;
            float s = red[(0 * 8 + b) * 64 + jl] + red[(1 * 8 + b) * 64 + jl]
                    + red[(2 * 8 + b) * 64 + jl] + red[(3 * 8 + b) * 64 + jl];
            part[((size_t)ks * 8 + b) * 2048 + j0 + jl] = s;
        }
    }
}

// ===== fp8 MFMA GEMM body: 128x64 tile, BK=128, DOUBLE-BUFFERED DMA =======
// One barrier per K-iter; tile k+1's DMA overlaps tile k's compute.
// MODE 0: bf16 C  MODE 1: f32 C + res  MODE 2: V-scatter pre-swizzled vT
template <int MODE>
__device__ __forceinline__ void gemm_body(const uchar* __restrict__ Ap,
                                          const uchar* __restrict__ Bp,
                                          const float* __restrict__ bias,
                                          const float* __restrict__ res,
                                          void* __restrict__ Cout,
                                          int m0, int n0, int Ncols, int K,
                                          uchar* Ash0, uchar* Ash1,
                                          uchar* Bsh0, uchar* Bsh1) {
    int tid = threadIdx.x;
    int w = tid >> 6, lane = tid & 63;
    int quad = lane >> 4, l15 = lane & 15;
    int wm = (w >> 1) * 64, wn = (w & 1) * 32;
    int lr8 = lane >> 3;
    int sc  = lane & 7;
    int gc  = sc ^ lr8;          // 16B chunk this lane fetches
    f32x4 acc[4][2] = {};
    // stage tile 0 into buffer 0
#pragma unroll
    for (int j = 0; j < 4; j++) {
        int rbase = w * 32 + j * 8;
        gld16(&Ap[(size_t)(m0 + rbase + lr8) * K + gc * 16], &Ash0[rbase * 128]);
    }
#pragma unroll
    for (int j = 0; j < 2; j++) {
        int rbase = w * 16 + j * 8;
        gld16(&Bp[(size_t)(n0 + rbase + lr8) * K + gc * 16], &Bsh0[rbase * 128]);
    }
    int nk = K >> 7;
    for (int ki = 0; ki < nk; ki++) {
        __syncthreads();   // drains DMA for tile ki (and prior ds_reads everywhere)
        uchar* Acur = (ki & 1) ? Ash1 : Ash0;
        uchar* Bcur = (ki & 1) ? Bsh1 : Bsh0;
        if (ki + 1 < nk) {
            uchar* Anxt = (ki & 1) ? Ash0 : Ash1;
            uchar* Bnxt = (ki & 1) ? Bsh0 : Bsh1;
            int kt = (ki + 1) << 7;
#pragma unroll
            for (int j = 0; j < 4; j++) {
                int rbase = w * 32 + j * 8;
                gld16(&Ap[(size_t)(m0 + rbase + lr8) * K + kt + gc * 16], &Anxt[rbase * 128]);
            }
#pragma unroll
            for (int j = 0; j < 2; j++) {
                int rbase = w * 16 + j * 8;
                gld16(&Bp[(size_t)(n0 + rbase + lr8) * K + kt + gc * 16], &Bnxt[rbase * 128]);
            }
        }
#pragma unroll
        for (int kh = 0; kh < 4; kh++) {
            int c4 = kh * 2 + (quad >> 1);
            int sub = (quad & 1) * 8;
            int pos = (c4 ^ (l15 & 7)) * 16 + sub;
            i64 af[4], bfr[2];
#pragma unroll
            for (int mt = 0; mt < 4; mt++)
                af[mt] = *(const i64*)&Acur[(wm + mt * 16 + l15) * 128 + pos];
#pragma unroll
            for (int nt = 0; nt < 2; nt++)
                bfr[nt] = *(const i64*)&Bcur[(wn + nt * 16 + l15) * 128 + pos];
#pragma unroll
            for (int mt = 0; mt < 4; mt++)
#pragma unroll
                for (int nt = 0; nt < 2; nt++)
                    acc[mt][nt] = __builtin_amdgcn_mfma_f32_16x16x32_fp8_fp8(af[mt], bfr[nt], acc[mt][nt], 0, 0, 0);
        }
    }
#pragma unroll
    for (int mt = 0; mt < 4; mt++) {
#pragma unroll
        for (int nt = 0; nt < 2; nt++) {
#pragma unroll
            for (int reg = 0; reg < 4; reg++) {
                int row = m0 + wm + mt * 16 + quad * 4 + reg;
                int col = n0 + wn + nt * 16 + l15;
                float v = acc[mt][nt][reg] + bias[col];
                if (MODE == 1) {
                    v += res[(size_t)row * Ncols + col];
                    ((float*)Cout)[(size_t)row * Ncols + col] = v;
                } else if (MODE == 0) {
                    ((bf16*)Cout)[(size_t)row * Ncols + col] = __float2bfloat16(v);
                } else {
                    int b = row >> 8, n = row & 255;
                    int h = col >> 6, d = col & 63;
                    size_t addr = ((size_t)(b * 16 + h) * 64 + d) * 256
                                + (((n >> 3) ^ (d & 7)) * 8) + (n & 7);
                    ((bf16*)Cout)[addr] = __float2bfloat16(v);
                }
            }
        }
    }
}

// ===== fused Q/K/V projection + emb2 tail. XCD-local m mapping ============
__global__ __launch_bounds__(256) void qkv_gemm(const uchar* __restrict__ xn8,
                                                const uchar* __restrict__ xfn8,
                                                const uchar* __restrict__ wq8,
                                                const uchar* __restrict__ wk8,
                                                const uchar* __restrict__ wv8,
                                                const float* __restrict__ bq,
                                                const float* __restrict__ bk,
                                                const float* __restrict__ bv,
                                                bf16* __restrict__ q,
                                                bf16* __restrict__ kbuf,
                                                bf16* __restrict__ vT,
                                                const float* __restrict__ part,
                                                const float* __restrict__ bemb,
                                                float* __restrict__ embo) {
    __shared__ __align__(16) uchar Ash[2][128 * 128];
    __shared__ __align__(16) uchar Bsh[2][64 * 128];
    int bid = blockIdx.x;
    if (bid < 1024) {
        gemm_body<0>(xn8, wq8, bq, nullptr, q,
                     (bid & 63) * 128, (bid >> 6) * 64, D_, D_,
                     Ash[0], Ash[1], Bsh[0], Bsh[1]);
    } else if (bid < 1280) {
        int id = bid - 1024;
        gemm_body<0>(xfn8, wk8, bk, nullptr, kbuf,
                     (id & 15) * 128, (id >> 4) * 64, D_, L_,
                     Ash[0], Ash[1], Bsh[0], Bsh[1]);
    } else if (bid < 1536) {
        int id = bid - 1280;
        gemm_body<2>(xfn8, wv8, bv, nullptr, vT,
                     (id & 15) * 128, (id >> 4) * 64, D_, L_,
                     Ash[0], Ash[1], Bsh[0], Bsh[1]);
    } else {
        int o = (bid - 1536) * 256 + threadIdx.x;
        int b = o >> 11, j = o & 2047;
        float s = bemb[j];
#pragma unroll
        for (int ks = 0; ks < 8; ks++) s += part[((size_t)ks * 8 + b) * 2048 + j];
        embo[o] = s;
    }
}

// ===== output projection + residual (f32 out) =============================
__global__ __launch_bounds__(256) void out_gemm(const uchar* __restrict__ a8,
                                                const uchar* __restrict__ wo8,
                                                const float* __restrict__ bout,
                                                const float* __restrict__ x,
                                                float* __restrict__ out) {
    __shared__ __align__(16) uchar Ash[2][128 * 128];
    __shared__ __align__(16) uchar Bsh[2][64 * 128];
    int bid = blockIdx.x;
    gemm_body<1>(a8, wo8, bout, x, out,
                 (bid & 63) * 128, (bid >> 6) * 64, D_, D_,
                 Ash[0], Ash[1], Bsh[0], Bsh[1]);
}

// ===== MFMA attention: block = 64 q-rows x one (b,h) (bf16, unchanged) ====
__global__ __launch_bounds__(256) void attn_mfma(const bf16* __restrict__ q,
                                                 const bf16* __restrict__ k,
                                                 const bf16* __restrict__ vT,
                                                 bf16* __restrict__ y) {
    __shared__ ushort KV[N_ * HD_];
    __shared__ ushort P[64 * N_];
    int tid = threadIdx.x;
    int w = tid >> 6, lane = tid & 63;
    int quad = lane >> 4, l15 = lane & 15;
    int t0 = blockIdx.x * 64;
    int bh = blockIdx.y;
    int b = bh >> 4, h = bh & 15;

    const ushort* kp = (const ushort*)k;
    const ushort* qp = (const ushort*)q;
    const ushort* vp = (const ushort*)vT;
    int lr8 = lane >> 3, sc = lane & 7, gc = sc ^ lr8;

#pragma unroll
    for (int j = 0; j < 8; j++) {
        int rbase = w * 64 + j * 8;
        gld16(&kp[(size_t)(b * N_ + rbase + lr8) * D_ + h * 64 + gc * 8], &KV[rbase * 64]);
    }
#pragma unroll
    for (int j = 0; j < 2; j++) {
        int rbase = w * 16 + j * 8;
        gld16(&qp[(size_t)(b * T_ + t0 + rbase + lr8) * D_ + h * 64 + gc * 8], &P[rbase * 64]);
    }
    __syncthreads();

    int qrow = w * 16 + l15;
    bf16x8 aq[2];
#pragma unroll
    for (int kk = 0; kk < 2; kk++)
        aq[kk] = *(bf16x8*)&P[qrow * 64 + (((kk * 4 + quad) ^ (qrow & 7)) * 8)];
    f32x4 sf[16];
#pragma unroll
    for (int nt = 0; nt < 16; nt++) {
        int n = nt * 16 + l15;
        bf16x8 b0 = *(bf16x8*)&KV[n * 64 + (((0 + quad) ^ (n & 7)) * 8)];
        bf16x8 b1 = *(bf16x8*)&KV[n * 64 + (((4 + quad) ^ (n & 7)) * 8)];
        f32x4 z = {};
        f32x4 t = __builtin_amdgcn_mfma_f32_16x16x32_bf16(aq[0], b0, z, 0, 0, 0);
        sf[nt] = __builtin_amdgcn_mfma_f32_16x16x32_bf16(aq[1], b1, t, 0, 0, 0);
    }
    __syncthreads();

    const ushort* vbase = vp + (size_t)(b * 16 + h) * 16384;
#pragma unroll
    for (int j = 0; j < 8; j++) {
        gld16(&vbase[(w * 8 + j) * 512 + lane * 8], &KV[(w * 8 + j) * 512]);
    }

    const float scale = 0.125f;
    float mx[4] = {-1e30f, -1e30f, -1e30f, -1e30f};
#pragma unroll
    for (int nt = 0; nt < 16; nt++)
#pragma unroll
        for (int reg = 0; reg < 4; reg++) mx[reg] = fmaxf(mx[reg], sf[nt][reg]);
#pragma unroll
    for (int off = 1; off < 16; off <<= 1)
#pragma unroll
        for (int reg = 0; reg < 4; reg++)
            mx[reg] = fmaxf(mx[reg], __shfl_xor(mx[reg], off, 64));
    float sm[4] = {0.f, 0.f, 0.f, 0.f};
#pragma unroll
    for (int nt = 0; nt < 16; nt++)
#pragma unroll
        for (int reg = 0; reg < 4; reg++) {
            float e = __expf((sf[nt][reg] - mx[reg]) * scale);
            sf[nt][reg] = e;
            sm[reg] += e;
        }
#pragma unroll
    for (int off = 1; off < 16; off <<= 1)
#pragma unroll
        for (int reg = 0; reg < 4; reg++)
            sm[reg] += __shfl_xor(sm[reg], off, 64);
    float inv[4];
#pragma unroll
    for (int reg = 0; reg < 4; reg++) inv[reg] = 1.f / sm[reg];

#pragma unroll
    for (int nt = 0; nt < 16; nt++)
#pragma unroll
        for (int reg = 0; reg < 4; reg++) {
            int r = w * 16 + quad * 4 + reg;
            int colc = nt * 2 + (l15 >> 3);
            int addr = r * 256 + ((colc ^ (r & 7)) * 8) + (l15 & 7);
            bf16 hv = __float2bfloat16(sf[nt][reg]);
            P[addr] = *(ushort*)&hv;
        }
    __syncthreads();

    f32x4 of[4] = {};
    int prow = w * 16 + l15;
#pragma unroll
    for (int kk = 0; kk < 8; kk++) {
        bf16x8 ap = *(bf16x8*)&P[prow * 256 + (((kk * 4 + quad) ^ (prow & 7)) * 8)];
#pragma unroll
        for (int dt = 0; dt < 4; dt++) {
            int d = dt * 16 + l15;
            bf16x8 bv = *(bf16x8*)&KV[d * 256 + (((kk * 4 + quad) ^ (d & 7)) * 8)];
            of[dt] = __builtin_amdgcn_mfma_f32_16x16x32_bf16(ap, bv, of[dt], 0, 0, 0);
        }
    }
#pragma unroll
    for (int dt = 0; dt < 4; dt++)
#pragma unroll
        for (int reg = 0; reg < 4; reg++) {
            int r = t0 + w * 16 + quad * 4 + reg;
            y[((size_t)(b * T_ + r) * D_) + h * 64 + dt * 16 + l15] =
                __float2bfloat16(of[dt][reg] * inv[reg]);
        }
}

// ===== stylization -> fp8 a-buf ===========================================
__global__ __launch_bounds__(256) void styl_kernel(const bf16* __restrict__ y,
                                                   const float* __restrict__ g,
                                                   const float* __restrict__ bb,
                                                   const float* __restrict__ embo,
                                                   uchar* __restrict__ a8) {
    int row = blockIdx.x;
    int b = row >> 10;
    int tid = threadIdx.x;
    const ushort* rp = (const ushort*)(y + (size_t)row * D_);
    ushort4 uy = *(const ushort4*)&rp[tid * 4];
    float v0 = bitf((unsigned)uy.x << 16), v1 = bitf((unsigned)uy.y << 16);
    float v2 = bitf((unsigned)uy.z << 16), v3 = bitf((unsigned)uy.w << 16);
    float s = v0 + v1 + v2 + v3;
    float s2 = v0 * v0 + v1 * v1 + v2 * v2 + v3 * v3;
    for (int off = 32; off; off >>= 1) {
        s  += __shfl_down(s,  off, 64);
        s2 += __shfl_down(s2, off, 64);
    }
    __shared__ float ps[4], ps2[4];
    __shared__ float smu, srstd;
    int wid = tid >> 6, lid = tid & 63;
    if (lid == 0) { ps[wid] = s; ps2[wid] = s2; }
    __syncthreads();
    if (tid == 0) {
        float t = ps[0] + ps[1] + ps[2] + ps[3];
        float t2 = ps2[0] + ps2[1] + ps2[2] + ps2[3];
        float m = t / D_;
        float var = t2 / D_ - m * m;
        smu = m; srstd = rsqrtf(var + 1e-5f);
    }
    __syncthreads();
    float mu = smu, rstd = srstd;
    float4 gv = *(const float4*)&g[tid * 4];
    float4 bv = *(const float4*)&bb[tid * 4];
    float4 scv = *(const float4*)&embo[b * 2048 + tid * 4];
    float4 shv = *(const float4*)&embo[b * 2048 + 1024 + tid * 4];
    float n0 = (v0 - mu) * rstd * gv.x + bv.x;
    float n1 = (v1 - mu) * rstd * gv.y + bv.y;
    float n2 = (v2 - mu) * rstd * gv.z + bv.z;
    float n3 = (v3 - mu) * rstd * gv.w + bv.w;
    float h0 = n0 * (1.f + scv.x) + shv.x;
    float h1 = n1 * (1.f + scv.y) + shv.y;
    float h2 = n2 * (1.f + scv.z) + shv.z;
    float h3 = n3 * (1.f + scv.w) + shv.w;
    h0 = h0 / (1.f + __expf(-h0));
    h1 = h1 / (1.f + __expf(-h1));
    h2 = h2 / (1.f + __expf(-h2));
    h3 = h3 / (1.f + __expf(-h3));
    *(int*)&a8[(size_t)row * D_ + tid * 4] = pk4_fp8(h0, h1, h2, h3);
}

extern "C" void kernel_launch(void* const* d_in, const int* in_sizes, int n_in,
                              void* d_out, int out_size, void* d_ws, size_t ws_size,
                              hipStream_t stream) {
    const float* x    = (const float*)d_in[0];
    const float* xf   = (const float*)d_in[1];
    const float* emb  = (const float*)d_in[2];
    const float* ln_g = (const float*)d_in[3];
    const float* ln_b = (const float*)d_in[4];
    const float* cln_g= (const float*)d_in[5];
    const float* cln_b= (const float*)d_in[6];
    const float* Wq   = (const float*)d_in[7];
    const float* bq   = (const float*)d_in[8];
    const float* Wk   = (const float*)d_in[9];
    const float* bk   = (const float*)d_in[10];
    const float* Wv   = (const float*)d_in[11];
    const float* bv   = (const float*)d_in[12];
    const float* sln_g= (const float*)d_in[13];
    const float* sln_b= (const float*)d_in[14];
    const float* Wemb = (const float*)d_in[15];
    const float* bemb = (const float*)d_in[16];
    const float* Wout = (const float*)d_in[17];
    const float* bout = (const float*)d_in[18];
    float* out = (float*)d_out;

    char* wsp = (char*)d_ws;
    const size_t MB = 1024 * 1024;
    uchar* xn8  = (uchar*)(wsp);                  // 8192x1024 fp8   8 MB
    uchar* xfn8 = (uchar*)(wsp + 8 * MB);         // 2048x768  fp8  1.5 MB
    uchar* wq8  = (uchar*)(wsp + 10 * MB);        // 1024x1024 fp8   1 MB
    uchar* wk8  = (uchar*)(wsp + 11 * MB);        // 1024x768  fp8  .75 MB
    uchar* wv8  = (uchar*)(wsp + 12 * MB);        // 1024x768  fp8  .75 MB
    uchar* wo8  = (uchar*)(wsp + 13 * MB);        // 1024x1024 fp8   1 MB
    bf16*  q    = (bf16*)(wsp + 14 * MB);         // 8192x1024 bf16 16 MB
    bf16*  kbuf = (bf16*)(wsp + 30 * MB);         // 2048x1024 bf16  4 MB
    bf16*  vT   = (bf16*)(wsp + 34 * MB);         // pre-swizzled     4 MB
    bf16*  ybuf = (bf16*)(wsp + 38 * MB);         // 8192x1024 bf16 16 MB
    uchar* a8   = (uchar*)(wsp + 54 * MB);        // 8192x1024 fp8   8 MB
    float* embo = (float*)(wsp + 62 * MB);        // 8x2048    f32  64 KB
    float* part = (float*)(wsp + 63 * MB);        // 8x8x2048  f32  512 KB

    prep_kernel<<<11392, 256, 0, stream>>>(x, xf, ln_g, ln_b, cln_g, cln_b,
                                           Wq, Wk, Wv, Wout, emb, Wemb,
                                           xn8, xfn8, wq8, wk8, wv8, wo8, part);

    qkv_gemm<<<1600, 256, 0, stream>>>(xn8, xfn8, wq8, wk8, wv8, bq, bk, bv,
                                       q, kbuf, vT, part, bemb, embo);

    attn_mfma<<<dim3(16, 128), 256, 0, stream>>>(q, kbuf, vT, ybuf);

    styl_kernel<<<B_ * T_, 256, 0, stream>>>(ybuf, sln_g, sln_b, embo, a8);

    out_gemm<<<1024, 256, 0, stream>>>(a8, wo8, bout, x, out);
}

// Round 10
// 236.763 us; speedup vs baseline: 1.0411x; 1.0411x over previous
//
#include <hip/hip_runtime.h>
#include <hip/hip_bf16.h>

typedef __hip_bfloat16 bf16;
typedef unsigned short ushort;
typedef unsigned char uchar;
typedef long i64;   // 64-bit on amdgcn
typedef __attribute__((ext_vector_type(8))) short bf16x8;
typedef __attribute__((ext_vector_type(4))) float f32x4;

#define B_ 8
#define T_ 1024
#define D_ 1024
#define N_ 256
#define L_ 768
#define H_ 16
#define HD_ 64
#define TE_ 2048

__device__ __forceinline__ void gld16(const void* g, void* l) {
    __builtin_amdgcn_global_load_lds((const __attribute__((address_space(1))) void*)g,
                                     (__attribute__((address_space(3))) void*)l,
                                     16, 0, 0);
}

__device__ __forceinline__ float bitf(unsigned u) { return __uint_as_float(u); }

// pack 4 f32 -> 4 fp8 e4m3 bytes (OCP on gfx950)
__device__ __forceinline__ int pk4_fp8(float a, float b, float c, float d) {
    int p = __builtin_amdgcn_cvt_pk_fp8_f32(a, b, 0, false);
    p = __builtin_amdgcn_cvt_pk_fp8_f32(c, d, p, true);
    return p;
}
__device__ __forceinline__ uchar pk1_fp8(float a) {
    int p = __builtin_amdgcn_cvt_pk_fp8_f32(a, a, 0, false);
    return (uchar)(p & 0xff);
}

// ===== prep: LN(x)+LN(xf)->fp8 [0,10240) | tcvt4->fp8 [10240,11136) | emb1 [11136,11392)
__global__ __launch_bounds__(256) void prep_kernel(
        const float* __restrict__ x, const float* __restrict__ xf,
        const float* __restrict__ g1, const float* __restrict__ b1,
        const float* __restrict__ g2, const float* __restrict__ b2,
        const float* __restrict__ Wq, const float* __restrict__ Wk,
        const float* __restrict__ Wv, const float* __restrict__ Wo,
        const float* __restrict__ emb, const float* __restrict__ Wemb,
        uchar* __restrict__ xn8, uchar* __restrict__ xfn8,
        uchar* __restrict__ wq8, uchar* __restrict__ wk8,
        uchar* __restrict__ wv8, uchar* __restrict__ wo8,
        float* __restrict__ part) {
    __shared__ __align__(16) char smem[16384];
    int bid = blockIdx.x;
    int tid = threadIdx.x;
    if (bid < 10240) {
        // LayerNorm, 4 cols/thread, fp8 out
        const float *rp, *g, *bb; uchar* op; int cols;
        if (bid < B_ * T_) {
            rp = x + (size_t)bid * D_; g = g1; bb = b1; op = xn8 + (size_t)bid * D_; cols = D_;
        } else {
            int r = bid - B_ * T_;
            rp = xf + (size_t)r * L_; g = g2; bb = b2; op = xfn8 + (size_t)r * L_; cols = L_;
        }
        float* ps  = (float*)smem;
        float* ps2 = ps + 4;
        float* st  = ps + 8;
        bool act = tid * 4 < cols;
        float4 v = act ? *(const float4*)&rp[tid * 4] : make_float4(0.f, 0.f, 0.f, 0.f);
        float s = v.x + v.y + v.z + v.w;
        float s2 = v.x * v.x + v.y * v.y + v.z * v.z + v.w * v.w;
        for (int off = 32; off; off >>= 1) {
            s  += __shfl_down(s,  off, 64);
            s2 += __shfl_down(s2, off, 64);
        }
        int wid = tid >> 6, lid = tid & 63;
        if (lid == 0) { ps[wid] = s; ps2[wid] = s2; }
        __syncthreads();
        if (tid == 0) {
            float t = ps[0] + ps[1] + ps[2] + ps[3];
            float t2 = ps2[0] + ps2[1] + ps2[2] + ps2[3];
            float m = t / cols;
            float var = t2 / cols - m * m;
            st[0] = m; st[1] = rsqrtf(var + 1e-5f);
        }
        __syncthreads();
        if (!act) return;
        float mu = st[0], rstd = st[1];
        float4 gv = *(const float4*)&g[tid * 4];
        float4 bv = *(const float4*)&bb[tid * 4];
        float o0 = (v.x - mu) * rstd * gv.x + bv.x;
        float o1 = (v.y - mu) * rstd * gv.y + bv.y;
        float o2 = (v.z - mu) * rstd * gv.z + bv.z;
        float o3 = (v.w - mu) * rstd * gv.w + bv.w;
        *(int*)&op[tid * 4] = pk4_fp8(o0, o1, o2, o3);
    } else if (bid < 11136) {
        // weight transpose + f32->fp8: W(KxNc) -> Wt(NcxK)
        uchar (*t)[65] = (uchar(*)[65])smem;
        int id = bid - 10240;
        int xb = id & 15, y = id >> 4;
        const float* W; uchar* Wt; int K, ky;
        if (y < 16)      { W = Wq; Wt = wq8; K = 1024; ky = y; }
        else if (y < 28) { W = Wk; Wt = wk8; K = 768;  ky = y - 16; }
        else if (y < 40) { W = Wv; Wt = wv8; K = 768;  ky = y - 28; }
        else             { W = Wo; Wt = wo8; K = 1024; ky = y - 40; }
        int k0 = ky * 64, n0 = xb * 64;
#pragma unroll
        for (int i = 0; i < 16; i++) {
            int e = tid + i * 256;
            int r = e >> 6, c = e & 63;
            t[r][c] = pk1_fp8(W[(size_t)(k0 + r) * D_ + n0 + c]);
        }
        __syncthreads();
#pragma unroll
        for (int i = 0; i < 4; i++) {
            int e = tid + i * 256;          // 1024 writes of 4B
            int r = e >> 4, cg = (e & 15) * 4;
            unsigned u = (unsigned)t[cg][r] | ((unsigned)t[cg + 1][r] << 8)
                       | ((unsigned)t[cg + 2][r] << 16) | ((unsigned)t[cg + 3][r] << 24);
            *(unsigned*)&Wt[(size_t)(n0 + r) * K + k0 + cg] = u;
        }
    } else {
        // emb1: silu(emb) @ Wemb partial dots
        float* se  = (float*)smem;
        float* red = (float*)(smem + 8192);
        int id = bid - 11136;
        int j0 = (id & 31) * 64;
        int ks = id >> 5;
        int tx = tid & 15, ty = tid >> 4;
        int w = tid >> 6, lane = tid & 63;
#pragma unroll
        for (int b = 0; b < 8; b++) {
            float xv = emb[b * TE_ + ks * 256 + tid];
            se[b * 256 + tid] = xv / (1.f + __expf(-xv));
        }
        __syncthreads();
        float acc[8][4] = {};
#pragma unroll 4
        for (int i = 0; i < 16; i++) {
            int e = ty + 16 * i;
            float4 wv = *(const float4*)&Wemb[(size_t)(ks * 256 + e) * 2048 + j0 + tx * 4];
#pragma unroll
            for (int b = 0; b < 8; b++) {
                float s = se[b * 256 + e];
                acc[b][0] += s * wv.x; acc[b][1] += s * wv.y;
                acc[b][2] += s * wv.z; acc[b][3] += s * wv.w;
            }
        }
#pragma unroll
        for (int b = 0; b < 8; b++)
#pragma unroll
            for (int m = 0; m < 4; m++) {
                float v = acc[b][m];
                v += __shfl_down(v, 32, 64);
                v += __shfl_down(v, 16, 64);
                if (lane < 16) red[(w * 8 + b) * 64 + lane * 4 + m] = v;
            }
        __syncthreads();
        for (int o = tid; o < 512; o += 256) {
            int b = o >> 6, jl = o & 63;
            float s = red[(0 * 8 + b) * 64 + jl] + red[(1 * 8 + b) * 64 + jl]
                    + red[(2 * 8 + b) * 64 + jl] + red[(3 * 8 + b) * 64 + jl];
            part[((size_t)ks * 8 + b) * 2048 + j0 + jl] = s;
        }
    }
}

// ===== fp8 MFMA GEMM body: 128x64 tile, BK=128, single-buffer DMA =========
// (dbuf reverted: compiler's vmcnt(0)-before-barrier drains any prefetch, and
//  48KB LDS cost 5->3 blocks/CU — measured regression R9. This is the R8 body.)
// MODE 0: bf16 C  MODE 1: f32 C + res  MODE 2: V-scatter pre-swizzled vT
template <int MODE>
__device__ __forceinline__ void gemm_body(const uchar* __restrict__ Ap,
                                          const uchar* __restrict__ Bp,
                                          const float* __restrict__ bias,
                                          const float* __restrict__ res,
                                          void* __restrict__ Cout,
                                          int m0, int n0, int Ncols, int K,
                                          uchar* Ash, uchar* Bsh) {
    int tid = threadIdx.x;
    int w = tid >> 6, lane = tid & 63;
    int quad = lane >> 4, l15 = lane & 15;
    int wm = (w >> 1) * 64, wn = (w & 1) * 32;
    int lr8 = lane >> 3;
    int sc  = lane & 7;
    int gc  = sc ^ lr8;          // 16B chunk this lane fetches
    f32x4 acc[4][2] = {};
    for (int kt = 0; kt < K; kt += 128) {
#pragma unroll
        for (int j = 0; j < 4; j++) {
            int rbase = w * 32 + j * 8;
            gld16(&Ap[(size_t)(m0 + rbase + lr8) * K + kt + gc * 16], &Ash[rbase * 128]);
        }
#pragma unroll
        for (int j = 0; j < 2; j++) {
            int rbase = w * 16 + j * 8;
            gld16(&Bp[(size_t)(n0 + rbase + lr8) * K + kt + gc * 16], &Bsh[rbase * 128]);
        }
        __syncthreads();
#pragma unroll
        for (int kh = 0; kh < 4; kh++) {
            int c4 = kh * 2 + (quad >> 1);
            int sub = (quad & 1) * 8;
            int pos = (c4 ^ (l15 & 7)) * 16 + sub;
            i64 af[4], bfr[2];
#pragma unroll
            for (int mt = 0; mt < 4; mt++)
                af[mt] = *(const i64*)&Ash[(wm + mt * 16 + l15) * 128 + pos];
#pragma unroll
            for (int nt = 0; nt < 2; nt++)
                bfr[nt] = *(const i64*)&Bsh[(wn + nt * 16 + l15) * 128 + pos];
#pragma unroll
            for (int mt = 0; mt < 4; mt++)
#pragma unroll
                for (int nt = 0; nt < 2; nt++)
                    acc[mt][nt] = __builtin_amdgcn_mfma_f32_16x16x32_fp8_fp8(af[mt], bfr[nt], acc[mt][nt], 0, 0, 0);
        }
        __syncthreads();
    }
#pragma unroll
    for (int mt = 0; mt < 4; mt++) {
#pragma unroll
        for (int nt = 0; nt < 2; nt++) {
#pragma unroll
            for (int reg = 0; reg < 4; reg++) {
                int row = m0 + wm + mt * 16 + quad * 4 + reg;
                int col = n0 + wn + nt * 16 + l15;
                float v = acc[mt][nt][reg] + bias[col];
                if (MODE == 1) {
                    v += res[(size_t)row * Ncols + col];
                    ((float*)Cout)[(size_t)row * Ncols + col] = v;
                } else if (MODE == 0) {
                    ((bf16*)Cout)[(size_t)row * Ncols + col] = __float2bfloat16(v);
                } else {
                    int b = row >> 8, n = row & 255;
                    int h = col >> 6, d = col & 63;
                    size_t addr = ((size_t)(b * 16 + h) * 64 + d) * 256
                                + (((n >> 3) ^ (d & 7)) * 8) + (n & 7);
                    ((bf16*)Cout)[addr] = __float2bfloat16(v);
                }
            }
        }
    }
}

// ===== fused Q/K/V projection + emb2 tail. XCD-local m mapping ============
__global__ __launch_bounds__(256) void qkv_gemm(const uchar* __restrict__ xn8,
                                                const uchar* __restrict__ xfn8,
                                                const uchar* __restrict__ wq8,
                                                const uchar* __restrict__ wk8,
                                                const uchar* __restrict__ wv8,
                                                const float* __restrict__ bq,
                                                const float* __restrict__ bk,
                                                const float* __restrict__ bv,
                                                bf16* __restrict__ q,
                                                bf16* __restrict__ kbuf,
                                                bf16* __restrict__ vT,
                                                const float* __restrict__ part,
                                                const float* __restrict__ bemb,
                                                float* __restrict__ embo) {
    __shared__ __align__(16) uchar Ash[128 * 128];
    __shared__ __align__(16) uchar Bsh[64 * 128];
    int bid = blockIdx.x;
    if (bid < 1024) {
        gemm_body<0>(xn8, wq8, bq, nullptr, q,
                     (bid & 63) * 128, (bid >> 6) * 64, D_, D_, Ash, Bsh);
    } else if (bid < 1280) {
        int id = bid - 1024;
        gemm_body<0>(xfn8, wk8, bk, nullptr, kbuf,
                     (id & 15) * 128, (id >> 4) * 64, D_, L_, Ash, Bsh);
    } else if (bid < 1536) {
        int id = bid - 1280;
        gemm_body<2>(xfn8, wv8, bv, nullptr, vT,
                     (id & 15) * 128, (id >> 4) * 64, D_, L_, Ash, Bsh);
    } else {
        int o = (bid - 1536) * 256 + threadIdx.x;
        int b = o >> 11, j = o & 2047;
        float s = bemb[j];
#pragma unroll
        for (int ks = 0; ks < 8; ks++) s += part[((size_t)ks * 8 + b) * 2048 + j];
        embo[o] = s;
    }
}

// ===== output projection + residual (f32 out) =============================
__global__ __launch_bounds__(256) void out_gemm(const uchar* __restrict__ a8,
                                                const uchar* __restrict__ wo8,
                                                const float* __restrict__ bout,
                                                const float* __restrict__ x,
                                                float* __restrict__ out) {
    __shared__ __align__(16) uchar Ash[128 * 128];
    __shared__ __align__(16) uchar Bsh[64 * 128];
    int bid = blockIdx.x;
    gemm_body<1>(a8, wo8, bout, x, out,
                 (bid & 63) * 128, (bid >> 6) * 64, D_, D_, Ash, Bsh);
}

// ===== MFMA attention: block = 64 q-rows x one (b,h) ======================
// Softmax WITHOUT max-subtraction: s ~ N(0,1), |s|max ~ 6 << 88 (f32 exp
// overflow); mathematically identical weights, saves the max pass.
__global__ __launch_bounds__(256) void attn_mfma(const bf16* __restrict__ q,
                                                 const bf16* __restrict__ k,
                                                 const bf16* __restrict__ vT,
                                                 bf16* __restrict__ y) {
    __shared__ ushort KV[N_ * HD_];
    __shared__ ushort P[64 * N_];
    int tid = threadIdx.x;
    int w = tid >> 6, lane = tid & 63;
    int quad = lane >> 4, l15 = lane & 15;
    int t0 = blockIdx.x * 64;
    int bh = blockIdx.y;
    int b = bh >> 4, h = bh & 15;

    const ushort* kp = (const ushort*)k;
    const ushort* qp = (const ushort*)q;
    const ushort* vp = (const ushort*)vT;
    int lr8 = lane >> 3, sc = lane & 7, gc = sc ^ lr8;

#pragma unroll
    for (int j = 0; j < 8; j++) {
        int rbase = w * 64 + j * 8;
        gld16(&kp[(size_t)(b * N_ + rbase + lr8) * D_ + h * 64 + gc * 8], &KV[rbase * 64]);
    }
#pragma unroll
    for (int j = 0; j < 2; j++) {
        int rbase = w * 16 + j * 8;
        gld16(&qp[(size_t)(b * T_ + t0 + rbase + lr8) * D_ + h * 64 + gc * 8], &P[rbase * 64]);
    }
    __syncthreads();

    int qrow = w * 16 + l15;
    bf16x8 aq[2];
#pragma unroll
    for (int kk = 0; kk < 2; kk++)
        aq[kk] = *(bf16x8*)&P[qrow * 64 + (((kk * 4 + quad) ^ (qrow & 7)) * 8)];
    f32x4 sf[16];
#pragma unroll
    for (int nt = 0; nt < 16; nt++) {
        int n = nt * 16 + l15;
        bf16x8 b0 = *(bf16x8*)&KV[n * 64 + (((0 + quad) ^ (n & 7)) * 8)];
        bf16x8 b1 = *(bf16x8*)&KV[n * 64 + (((4 + quad) ^ (n & 7)) * 8)];
        f32x4 z = {};
        f32x4 t = __builtin_amdgcn_mfma_f32_16x16x32_bf16(aq[0], b0, z, 0, 0, 0);
        sf[nt] = __builtin_amdgcn_mfma_f32_16x16x32_bf16(aq[1], b1, t, 0, 0, 0);
    }
    __syncthreads();   // all K reads done -> KV reusable for V

    // V DMA (identity copy of pre-swizzled vT) — latency hidden under softmax
    const ushort* vbase = vp + (size_t)(b * 16 + h) * 16384;
#pragma unroll
    for (int j = 0; j < 8; j++) {
        gld16(&vbase[(w * 8 + j) * 512 + lane * 8], &KV[(w * 8 + j) * 512]);
    }

    // softmax over N (rows = quad*4+reg), no max-subtraction
    const float scale = 0.125f;
    float sm[4] = {0.f, 0.f, 0.f, 0.f};
#pragma unroll
    for (int nt = 0; nt < 16; nt++)
#pragma unroll
        for (int reg = 0; reg < 4; reg++) {
            float e = __expf(sf[nt][reg] * scale);
            sf[nt][reg] = e;
            sm[reg] += e;
        }
#pragma unroll
    for (int off = 1; off < 16; off <<= 1)
#pragma unroll
        for (int reg = 0; reg < 4; reg++)
            sm[reg] += __shfl_xor(sm[reg], off, 64);
    float inv[4];
#pragma unroll
    for (int reg = 0; reg < 4; reg++) inv[reg] = 1.f / sm[reg];

#pragma unroll
    for (int nt = 0; nt < 16; nt++)
#pragma unroll
        for (int reg = 0; reg < 4; reg++) {
            int r = w * 16 + quad * 4 + reg;
            int colc = nt * 2 + (l15 >> 3);
            int addr = r * 256 + ((colc ^ (r & 7)) * 8) + (l15 & 7);
            bf16 hv = __float2bfloat16(sf[nt][reg]);
            P[addr] = *(ushort*)&hv;
        }
    __syncthreads();   // drains V DMA + P writes visible

    f32x4 of[4] = {};
    int prow = w * 16 + l15;
#pragma unroll
    for (int kk = 0; kk < 8; kk++) {
        bf16x8 ap = *(bf16x8*)&P[prow * 256 + (((kk * 4 + quad) ^ (prow & 7)) * 8)];
#pragma unroll
        for (int dt = 0; dt < 4; dt++) {
            int d = dt * 16 + l15;
            bf16x8 bv = *(bf16x8*)&KV[d * 256 + (((kk * 4 + quad) ^ (d & 7)) * 8)];
            of[dt] = __builtin_amdgcn_mfma_f32_16x16x32_bf16(ap, bv, of[dt], 0, 0, 0);
        }
    }
#pragma unroll
    for (int dt = 0; dt < 4; dt++)
#pragma unroll
        for (int reg = 0; reg < 4; reg++) {
            int r = t0 + w * 16 + quad * 4 + reg;
            y[((size_t)(b * T_ + r) * D_) + h * 64 + dt * 16 + l15] =
                __float2bfloat16(of[dt][reg] * inv[reg]);
        }
}

// ===== stylization -> fp8 a-buf ===========================================
__global__ __launch_bounds__(256) void styl_kernel(const bf16* __restrict__ y,
                                                   const float* __restrict__ g,
                                                   const float* __restrict__ bb,
                                                   const float* __restrict__ embo,
                                                   uchar* __restrict__ a8) {
    int row = blockIdx.x;
    int b = row >> 10;
    int tid = threadIdx.x;
    const ushort* rp = (const ushort*)(y + (size_t)row * D_);
    ushort4 uy = *(const ushort4*)&rp[tid * 4];
    float v0 = bitf((unsigned)uy.x << 16), v1 = bitf((unsigned)uy.y << 16);
    float v2 = bitf((unsigned)uy.z << 16), v3 = bitf((unsigned)uy.w << 16);
    float s = v0 + v1 + v2 + v3;
    float s2 = v0 * v0 + v1 * v1 + v2 * v2 + v3 * v3;
    for (int off = 32; off; off >>= 1) {
        s  += __shfl_down(s,  off, 64);
        s2 += __shfl_down(s2, off, 64);
    }
    __shared__ float ps[4], ps2[4];
    __shared__ float smu, srstd;
    int wid = tid >> 6, lid = tid & 63;
    if (lid == 0) { ps[wid] = s; ps2[wid] = s2; }
    __syncthreads();
    if (tid == 0) {
        float t = ps[0] + ps[1] + ps[2] + ps[3];
        float t2 = ps2[0] + ps2[1] + ps2[2] + ps2[3];
        float m = t / D_;
        float var = t2 / D_ - m * m;
        smu = m; srstd = rsqrtf(var + 1e-5f);
    }
    __syncthreads();
    float mu = smu, rstd = srstd;
    float4 gv = *(const float4*)&g[tid * 4];
    float4 bv = *(const float4*)&bb[tid * 4];
    float4 scv = *(const float4*)&embo[b * 2048 + tid * 4];
    float4 shv = *(const float4*)&embo[b * 2048 + 1024 + tid * 4];
    float n0 = (v0 - mu) * rstd * gv.x + bv.x;
    float n1 = (v1 - mu) * rstd * gv.y + bv.y;
    float n2 = (v2 - mu) * rstd * gv.z + bv.z;
    float n3 = (v3 - mu) * rstd * gv.w + bv.w;
    float h0 = n0 * (1.f + scv.x) + shv.x;
    float h1 = n1 * (1.f + scv.y) + shv.y;
    float h2 = n2 * (1.f + scv.z) + shv.z;
    float h3 = n3 * (1.f + scv.w) + shv.w;
    h0 = h0 / (1.f + __expf(-h0));
    h1 = h1 / (1.f + __expf(-h1));
    h2 = h2 / (1.f + __expf(-h2));
    h3 = h3 / (1.f + __expf(-h3));
    *(int*)&a8[(size_t)row * D_ + tid * 4] = pk4_fp8(h0, h1, h2, h3);
}

extern "C" void kernel_launch(void* const* d_in, const int* in_sizes, int n_in,
                              void* d_out, int out_size, void* d_ws, size_t ws_size,
                              hipStream_t stream) {
    const float* x    = (const float*)d_in[0];
    const float* xf   = (const float*)d_in[1];
    const float* emb  = (const float*)d_in[2];
    const float* ln_g = (const float*)d_in[3];
    const float* ln_b = (const float*)d_in[4];
    const float* cln_g= (const float*)d_in[5];
    const float* cln_b= (const float*)d_in[6];
    const float* Wq   = (const float*)d_in[7];
    const float* bq   = (const float*)d_in[8];
    const float* Wk   = (const float*)d_in[9];
    const float* bk   = (const float*)d_in[10];
    const float* Wv   = (const float*)d_in[11];
    const float* bv   = (const float*)d_in[12];
    const float* sln_g= (const float*)d_in[13];
    const float* sln_b= (const float*)d_in[14];
    const float* Wemb = (const float*)d_in[15];
    const float* bemb = (const float*)d_in[16];
    const float* Wout = (const float*)d_in[17];
    const float* bout = (const float*)d_in[18];
    float* out = (float*)d_out;

    char* wsp = (char*)d_ws;
    const size_t MB = 1024 * 1024;
    uchar* xn8  = (uchar*)(wsp);                  // 8192x1024 fp8   8 MB
    uchar* xfn8 = (uchar*)(wsp + 8 * MB);         // 2048x768  fp8  1.5 MB
    uchar* wq8  = (uchar*)(wsp + 10 * MB);        // 1024x1024 fp8   1 MB
    uchar* wk8  = (uchar*)(wsp + 11 * MB);        // 1024x768  fp8  .75 MB
    uchar* wv8  = (uchar*)(wsp + 12 * MB);        // 1024x768  fp8  .75 MB
    uchar* wo8  = (uchar*)(wsp + 13 * MB);        // 1024x1024 fp8   1 MB
    bf16*  q    = (bf16*)(wsp + 14 * MB);         // 8192x1024 bf16 16 MB
    bf16*  kbuf = (bf16*)(wsp + 30 * MB);         // 2048x1024 bf16  4 MB
    bf16*  vT   = (bf16*)(wsp + 34 * MB);         // pre-swizzled     4 MB
    bf16*  ybuf = (bf16*)(wsp + 38 * MB);         // 8192x1024 bf16 16 MB
    uchar* a8   = (uchar*)(wsp + 54 * MB);        // 8192x1024 fp8   8 MB
    float* embo = (float*)(wsp + 62 * MB);        // 8x2048    f32  64 KB
    float* part = (float*)(wsp + 63 * MB);        // 8x8x2048  f32  512 KB

    prep_kernel<<<11392, 256, 0, stream>>>(x, xf, ln_g, ln_b, cln_g, cln_b,
                                           Wq, Wk, Wv, Wout, emb, Wemb,
                                           xn8, xfn8, wq8, wk8, wv8, wo8, part);

    qkv_gemm<<<1600, 256, 0, stream>>>(xn8, xfn8, wq8, wk8, wv8, bq, bk, bv,
                                       q, kbuf, vT, part, bemb, embo);

    attn_mfma<<<dim3(16, 128), 256, 0, stream>>>(q, kbuf, vT, ybuf);

    styl_kernel<<<B_ * T_, 256, 0, stream>>>(ybuf, sln_g, sln_b, embo, a8);

    out_gemm<<<1024, 256, 0, stream>>>(a8, wo8, bout, x, out);
}

// Round 11
// 231.215 us; speedup vs baseline: 1.0661x; 1.0240x over previous
//
#include <hip/hip_runtime.h>
#include <hip/hip_bf16.h>

typedef __hip_bfloat16 bf16;
typedef unsigned short ushort;
typedef unsigned char uchar;
typedef long i64;   // 64-bit on amdgcn
typedef __attribute__((ext_vector_type(4))) float f32x4;

#define B_ 8
#define T_ 1024
#define D_ 1024
#define N_ 256
#define L_ 768
#define H_ 16
#define HD_ 64
#define TE_ 2048

__device__ __forceinline__ void gld16(const void* g, void* l) {
    __builtin_amdgcn_global_load_lds((const __attribute__((address_space(1))) void*)g,
                                     (__attribute__((address_space(3))) void*)l,
                                     16, 0, 0);
}

__device__ __forceinline__ float bitf(unsigned u) { return __uint_as_float(u); }

// pack 4 f32 -> 4 fp8 e4m3 bytes (OCP on gfx950)
__device__ __forceinline__ int pk4_fp8(float a, float b, float c, float d) {
    int p = __builtin_amdgcn_cvt_pk_fp8_f32(a, b, 0, false);
    p = __builtin_amdgcn_cvt_pk_fp8_f32(c, d, p, true);
    return p;
}
__device__ __forceinline__ uchar pk1_fp8(float a) {
    int p = __builtin_amdgcn_cvt_pk_fp8_f32(a, a, 0, false);
    return (uchar)(p & 0xff);
}
// manual e4m3fn decode (avoids unverified cvt builtin)
__device__ __forceinline__ float dec8(uchar b) {
    int e = (b >> 3) & 15, m = b & 7;
    float mag = e ? (float)(8 + m) * bitf((unsigned)(117 + e) << 23)   // (1+m/8)*2^(e-7)
                  : (float)m * bitf(118u << 23);                        // m * 2^-9
    return (b & 0x80) ? -mag : mag;
}

// ===== prep: LN(x)+LN(xf)->fp8 [0,10240) | tcvt4->fp8 [10240,11136) | emb1 [11136,11392)
__global__ __launch_bounds__(256) void prep_kernel(
        const float* __restrict__ x, const float* __restrict__ xf,
        const float* __restrict__ g1, const float* __restrict__ b1,
        const float* __restrict__ g2, const float* __restrict__ b2,
        const float* __restrict__ Wq, const float* __restrict__ Wk,
        const float* __restrict__ Wv, const float* __restrict__ Wo,
        const float* __restrict__ emb, const float* __restrict__ Wemb,
        uchar* __restrict__ xn8, uchar* __restrict__ xfn8,
        uchar* __restrict__ wq8, uchar* __restrict__ wk8,
        uchar* __restrict__ wv8, uchar* __restrict__ wo8,
        float* __restrict__ part) {
    __shared__ __align__(16) char smem[16384];
    int bid = blockIdx.x;
    int tid = threadIdx.x;
    if (bid < 10240) {
        const float *rp, *g, *bb; uchar* op; int cols;
        if (bid < B_ * T_) {
            rp = x + (size_t)bid * D_; g = g1; bb = b1; op = xn8 + (size_t)bid * D_; cols = D_;
        } else {
            int r = bid - B_ * T_;
            rp = xf + (size_t)r * L_; g = g2; bb = b2; op = xfn8 + (size_t)r * L_; cols = L_;
        }
        float* ps  = (float*)smem;
        float* ps2 = ps + 4;
        float* st  = ps + 8;
        bool act = tid * 4 < cols;
        float4 v = act ? *(const float4*)&rp[tid * 4] : make_float4(0.f, 0.f, 0.f, 0.f);
        float s = v.x + v.y + v.z + v.w;
        float s2 = v.x * v.x + v.y * v.y + v.z * v.z + v.w * v.w;
        for (int off = 32; off; off >>= 1) {
            s  += __shfl_down(s,  off, 64);
            s2 += __shfl_down(s2, off, 64);
        }
        int wid = tid >> 6, lid = tid & 63;
        if (lid == 0) { ps[wid] = s; ps2[wid] = s2; }
        __syncthreads();
        if (tid == 0) {
            float t = ps[0] + ps[1] + ps[2] + ps[3];
            float t2 = ps2[0] + ps2[1] + ps2[2] + ps2[3];
            float m = t / cols;
            float var = t2 / cols - m * m;
            st[0] = m; st[1] = rsqrtf(var + 1e-5f);
        }
        __syncthreads();
        if (!act) return;
        float mu = st[0], rstd = st[1];
        float4 gv = *(const float4*)&g[tid * 4];
        float4 bv = *(const float4*)&bb[tid * 4];
        float o0 = (v.x - mu) * rstd * gv.x + bv.x;
        float o1 = (v.y - mu) * rstd * gv.y + bv.y;
        float o2 = (v.z - mu) * rstd * gv.z + bv.z;
        float o3 = (v.w - mu) * rstd * gv.w + bv.w;
        *(int*)&op[tid * 4] = pk4_fp8(o0, o1, o2, o3);
    } else if (bid < 11136) {
        uchar (*t)[65] = (uchar(*)[65])smem;
        int id = bid - 10240;
        int xb = id & 15, y = id >> 4;
        const float* W; uchar* Wt; int K, ky;
        if (y < 16)      { W = Wq; Wt = wq8; K = 1024; ky = y; }
        else if (y < 28) { W = Wk; Wt = wk8; K = 768;  ky = y - 16; }
        else if (y < 40) { W = Wv; Wt = wv8; K = 768;  ky = y - 28; }
        else             { W = Wo; Wt = wo8; K = 1024; ky = y - 40; }
        int k0 = ky * 64, n0 = xb * 64;
#pragma unroll
        for (int i = 0; i < 16; i++) {
            int e = tid + i * 256;
            int r = e >> 6, c = e & 63;
            t[r][c] = pk1_fp8(W[(size_t)(k0 + r) * D_ + n0 + c]);
        }
        __syncthreads();
#pragma unroll
        for (int i = 0; i < 4; i++) {
            int e = tid + i * 256;
            int r = e >> 4, cg = (e & 15) * 4;
            unsigned u = (unsigned)t[cg][r] | ((unsigned)t[cg + 1][r] << 8)
                       | ((unsigned)t[cg + 2][r] << 16) | ((unsigned)t[cg + 3][r] << 24);
            *(unsigned*)&Wt[(size_t)(n0 + r) * K + k0 + cg] = u;
        }
    } else {
        float* se  = (float*)smem;
        float* red = (float*)(smem + 8192);
        int id = bid - 11136;
        int j0 = (id & 31) * 64;
        int ks = id >> 5;
        int tx = tid & 15, ty = tid >> 4;
        int w = tid >> 6, lane = tid & 63;
#pragma unroll
        for (int b = 0; b < 8; b++) {
            float xv = emb[b * TE_ + ks * 256 + tid];
            se[b * 256 + tid] = xv / (1.f + __expf(-xv));
        }
        __syncthreads();
        float acc[8][4] = {};
#pragma unroll 4
        for (int i = 0; i < 16; i++) {
            int e = ty + 16 * i;
            float4 wv = *(const float4*)&Wemb[(size_t)(ks * 256 + e) * 2048 + j0 + tx * 4];
#pragma unroll
            for (int b = 0; b < 8; b++) {
                float s = se[b * 256 + e];
                acc[b][0] += s * wv.x; acc[b][1] += s * wv.y;
                acc[b][2] += s * wv.z; acc[b][3] += s * wv.w;
            }
        }
#pragma unroll
        for (int b = 0; b < 8; b++)
#pragma unroll
            for (int m = 0; m < 4; m++) {
                float v = acc[b][m];
                v += __shfl_down(v, 32, 64);
                v += __shfl_down(v, 16, 64);
                if (lane < 16) red[(w * 8 + b) * 64 + lane * 4 + m] = v;
            }
        __syncthreads();
        for (int o = tid; o < 512; o += 256) {
            int b = o >> 6, jl = o & 63;
            float s = red[(0 * 8 + b) * 64 + jl] + red[(1 * 8 + b) * 64 + jl]
                    + red[(2 * 8 + b) * 64 + jl] + red[(3 * 8 + b) * 64 + jl];
            part[((size_t)ks * 8 + b) * 2048 + j0 + jl] = s;
        }
    }
}

// ===== fp8 MFMA GEMM body: 128x64 tile, BK=128, single-buffer DMA =========
// MODE 0: fp8 C  MODE 1: f32 C + res  MODE 2: V-scatter pre-swizzled vT8
template <int MODE>
__device__ __forceinline__ void gemm_body(const uchar* __restrict__ Ap,
                                          const uchar* __restrict__ Bp,
                                          const float* __restrict__ bias,
                                          const float* __restrict__ res,
                                          void* __restrict__ Cout,
                                          int m0, int n0, int Ncols, int K,
                                          uchar* Ash, uchar* Bsh) {
    int tid = threadIdx.x;
    int w = tid >> 6, lane = tid & 63;
    int quad = lane >> 4, l15 = lane & 15;
    int wm = (w >> 1) * 64, wn = (w & 1) * 32;
    int lr8 = lane >> 3;
    int sc  = lane & 7;
    int gc  = sc ^ lr8;
    f32x4 acc[4][2] = {};
    for (int kt = 0; kt < K; kt += 128) {
#pragma unroll
        for (int j = 0; j < 4; j++) {
            int rbase = w * 32 + j * 8;
            gld16(&Ap[(size_t)(m0 + rbase + lr8) * K + kt + gc * 16], &Ash[rbase * 128]);
        }
#pragma unroll
        for (int j = 0; j < 2; j++) {
            int rbase = w * 16 + j * 8;
            gld16(&Bp[(size_t)(n0 + rbase + lr8) * K + kt + gc * 16], &Bsh[rbase * 128]);
        }
        __syncthreads();
#pragma unroll
        for (int kh = 0; kh < 4; kh++) {
            int c4 = kh * 2 + (quad >> 1);
            int sub = (quad & 1) * 8;
            int pos = (c4 ^ (l15 & 7)) * 16 + sub;
            i64 af[4], bfr[2];
#pragma unroll
            for (int mt = 0; mt < 4; mt++)
                af[mt] = *(const i64*)&Ash[(wm + mt * 16 + l15) * 128 + pos];
#pragma unroll
            for (int nt = 0; nt < 2; nt++)
                bfr[nt] = *(const i64*)&Bsh[(wn + nt * 16 + l15) * 128 + pos];
#pragma unroll
            for (int mt = 0; mt < 4; mt++)
#pragma unroll
                for (int nt = 0; nt < 2; nt++)
                    acc[mt][nt] = __builtin_amdgcn_mfma_f32_16x16x32_fp8_fp8(af[mt], bfr[nt], acc[mt][nt], 0, 0, 0);
        }
        __syncthreads();
    }
#pragma unroll
    for (int mt = 0; mt < 4; mt++) {
#pragma unroll
        for (int nt = 0; nt < 2; nt++) {
#pragma unroll
            for (int reg = 0; reg < 4; reg++) {
                int row = m0 + wm + mt * 16 + quad * 4 + reg;
                int col = n0 + wn + nt * 16 + l15;
                float v = acc[mt][nt][reg] + bias[col];
                if (MODE == 1) {
                    v += res[(size_t)row * Ncols + col];
                    ((float*)Cout)[(size_t)row * Ncols + col] = v;
                } else if (MODE == 0) {
                    ((uchar*)Cout)[(size_t)row * Ncols + col] = pk1_fp8(v);
                } else {
                    int b = row >> 8, n = row & 255;
                    int h = col >> 6, d = col & 63;
                    size_t addr = ((size_t)(b * 16 + h)) * 16384 + (size_t)d * 256
                                + (((n >> 4) ^ (d & 15)) * 16) + (n & 15);
                    ((uchar*)Cout)[addr] = pk1_fp8(v);
                }
            }
        }
    }
}

// ===== fused Q/K/V projection + emb2 tail. XCD-local m mapping ============
__global__ __launch_bounds__(256) void qkv_gemm(const uchar* __restrict__ xn8,
                                                const uchar* __restrict__ xfn8,
                                                const uchar* __restrict__ wq8,
                                                const uchar* __restrict__ wk8,
                                                const uchar* __restrict__ wv8,
                                                const float* __restrict__ bq,
                                                const float* __restrict__ bk,
                                                const float* __restrict__ bv,
                                                uchar* __restrict__ q8,
                                                uchar* __restrict__ k8,
                                                uchar* __restrict__ vT8,
                                                const float* __restrict__ part,
                                                const float* __restrict__ bemb,
                                                float* __restrict__ embo) {
    __shared__ __align__(16) uchar Ash[128 * 128];
    __shared__ __align__(16) uchar Bsh[64 * 128];
    int bid = blockIdx.x;
    if (bid < 1024) {
        gemm_body<0>(xn8, wq8, bq, nullptr, q8,
                     (bid & 63) * 128, (bid >> 6) * 64, D_, D_, Ash, Bsh);
    } else if (bid < 1280) {
        int id = bid - 1024;
        gemm_body<0>(xfn8, wk8, bk, nullptr, k8,
                     (id & 15) * 128, (id >> 4) * 64, D_, L_, Ash, Bsh);
    } else if (bid < 1536) {
        int id = bid - 1280;
        gemm_body<2>(xfn8, wv8, bv, nullptr, vT8,
                     (id & 15) * 128, (id >> 4) * 64, D_, L_, Ash, Bsh);
    } else {
        int o = (bid - 1536) * 256 + threadIdx.x;
        int b = o >> 11, j = o & 2047;
        float s = bemb[j];
#pragma unroll
        for (int ks = 0; ks < 8; ks++) s += part[((size_t)ks * 8 + b) * 2048 + j];
        embo[o] = s;
    }
}

// ===== output projection + residual (f32 out) =============================
__global__ __launch_bounds__(256) void out_gemm(const uchar* __restrict__ a8,
                                                const uchar* __restrict__ wo8,
                                                const float* __restrict__ bout,
                                                const float* __restrict__ x,
                                                float* __restrict__ out) {
    __shared__ __align__(16) uchar Ash[128 * 128];
    __shared__ __align__(16) uchar Bsh[64 * 128];
    int bid = blockIdx.x;
    gemm_body<1>(a8, wo8, bout, x, out,
                 (bid & 63) * 128, (bid >> 6) * 64, D_, D_, Ash, Bsh);
}

// ===== full-fp8 MFMA attention: block = 64 q-rows x one (b,h) =============
// LDS 32 KB -> ~5 blocks/CU. K: 2 rows interleaved per 128B line, 8-chunk XOR.
// Q: padded 128B rows (4 valid chunks swizzled over 8 slots). P/V: 256B rows,
// 16-chunk XOR. Softmax without max-subtraction (|s|<~8, no overflow).
__global__ __launch_bounds__(256) void attn_mfma(const uchar* __restrict__ q8,
                                                 const uchar* __restrict__ k8,
                                                 const uchar* __restrict__ vT8,
                                                 uchar* __restrict__ y8) {
    __shared__ __align__(16) uchar KV[16384];  // K image, then V image
    __shared__ __align__(16) uchar P[16384];   // padded Q (first 8 KB), then P rows
    int tid = threadIdx.x;
    int w = tid >> 6, lane = tid & 63;
    int quad = lane >> 4, l15 = lane & 15;
    int t0 = blockIdx.x * 64;
    int bh = blockIdx.y;
    int b = bh >> 4, h = bh & 15;
    int lln = lane >> 3, sp = lane & 7;

    // K DMA: 4 gld16/wave; line dn holds rows 2dn,2dn+1; slot p <- chunk c8=p^(dn&7)
#pragma unroll
    for (int j = 0; j < 4; j++) {
        int dn = w * 32 + j * 8 + lln;
        int c8 = sp ^ (dn & 7);
        int n = dn * 2 + (c8 >> 2);
        gld16(&k8[(size_t)(b * N_ + n) * D_ + h * 64 + (c8 & 3) * 16],
              &KV[(w * 32 + j * 8) * 128]);
    }
    // Q DMA into P region: 2 gld16/wave; row r padded to 128B, slot p <- chunk (p^(r&7))&3
#pragma unroll
    for (int j = 0; j < 2; j++) {
        int r = w * 16 + j * 8 + lln;
        int c = (sp ^ (r & 7)) & 3;
        gld16(&q8[(size_t)(b * T_ + t0 + r) * D_ + h * 64 + c * 16],
              &P[(w * 16 + j * 8) * 128]);
    }
    __syncthreads();

    // S = Q K^T (fp8 mfma, K-dim 64 = 2 steps)
    int qrow = w * 16 + l15;
    i64 aq[2];
#pragma unroll
    for (int kk2 = 0; kk2 < 2; kk2++) {
        int chunk = kk2 * 2 + (quad >> 1);
        aq[kk2] = *(const i64*)&P[qrow * 128 + ((chunk ^ (qrow & 7)) * 16) + (quad & 1) * 8];
    }
    f32x4 sf[16];
#pragma unroll
    for (int nt = 0; nt < 16; nt++) {
        int n = nt * 16 + l15;
        int dn = n >> 1, hn = n & 1;
        int c80 = (hn * 4 + 0 + (quad >> 1)) ^ (dn & 7);
        int c81 = (hn * 4 + 2 + (quad >> 1)) ^ (dn & 7);
        i64 b0 = *(const i64*)&KV[dn * 128 + c80 * 16 + (quad & 1) * 8];
        i64 b1 = *(const i64*)&KV[dn * 128 + c81 * 16 + (quad & 1) * 8];
        f32x4 z = {};
        f32x4 t = __builtin_amdgcn_mfma_f32_16x16x32_fp8_fp8(aq[0], b0, z, 0, 0, 0);
        sf[nt] = __builtin_amdgcn_mfma_f32_16x16x32_fp8_fp8(aq[1], b1, t, 0, 0, 0);
    }
    __syncthreads();   // K reads done -> KV reusable for V

    // V DMA (identity copy of pre-swizzled vT8) — latency hidden under softmax
    const uchar* vbase = vT8 + (size_t)(b * 16 + h) * 16384;
#pragma unroll
    for (int j = 0; j < 4; j++) {
        gld16(&vbase[(w * 4 + j) * 1024 + lane * 16], &KV[(w * 4 + j) * 1024]);
    }

    // softmax over N (rows = quad*4+reg), no max-subtraction
    const float scale = 0.125f;
    float sm[4] = {0.f, 0.f, 0.f, 0.f};
#pragma unroll
    for (int nt = 0; nt < 16; nt++)
#pragma unroll
        for (int reg = 0; reg < 4; reg++) {
            float e = __expf(sf[nt][reg] * scale);
            sf[nt][reg] = e;
            sm[reg] += e;
        }
#pragma unroll
    for (int off = 1; off < 16; off <<= 1)
#pragma unroll
        for (int reg = 0; reg < 4; reg++)
            sm[reg] += __shfl_xor(sm[reg], off, 64);
    float inv[4];
#pragma unroll
    for (int reg = 0; reg < 4; reg++) inv[reg] = 1.f / sm[reg];

    // P writes (fp8 bytes, A-operand-ready layout) — overwrites Q (dead)
#pragma unroll
    for (int nt = 0; nt < 16; nt++)
#pragma unroll
        for (int reg = 0; reg < 4; reg++) {
            int r = w * 16 + quad * 4 + reg;
            int n = nt * 16 + l15;
            P[r * 256 + (((n >> 4) ^ (r & 15)) * 16) + (n & 15)] = pk1_fp8(sf[nt][reg]);
        }
    __syncthreads();   // drains V DMA + P writes visible

    // O = P @ V (fp8 mfma, K-dim 256 = 8 steps)
    f32x4 of[4] = {};
    int prow = w * 16 + l15;
#pragma unroll
    for (int kk = 0; kk < 8; kk++) {
        int ck = kk * 2 + (quad >> 1);
        i64 ap = *(const i64*)&P[prow * 256 + ((ck ^ (prow & 15)) * 16) + (quad & 1) * 8];
#pragma unroll
        for (int dt = 0; dt < 4; dt++) {
            int d = dt * 16 + l15;
            i64 bv = *(const i64*)&KV[d * 256 + ((ck ^ (d & 15)) * 16) + (quad & 1) * 8];
            of[dt] = __builtin_amdgcn_mfma_f32_16x16x32_fp8_fp8(ap, bv, of[dt], 0, 0, 0);
        }
    }
#pragma unroll
    for (int dt = 0; dt < 4; dt++)
#pragma unroll
        for (int reg = 0; reg < 4; reg++) {
            int r = t0 + w * 16 + quad * 4 + reg;
            y8[(size_t)(b * T_ + r) * D_ + h * 64 + dt * 16 + l15] =
                pk1_fp8(of[dt][reg] * inv[reg]);
        }
}

// ===== stylization: fp8 y in -> fp8 a out =================================
__global__ __launch_bounds__(256) void styl_kernel(const uchar* __restrict__ y8,
                                                   const float* __restrict__ g,
                                                   const float* __restrict__ bb,
                                                   const float* __restrict__ embo,
                                                   uchar* __restrict__ a8) {
    int row = blockIdx.x;
    int b = row >> 10;
    int tid = threadIdx.x;
    const uchar* rp = y8 + (size_t)row * D_;
    uchar4 uy = *(const uchar4*)&rp[tid * 4];
    float v0 = dec8(uy.x), v1 = dec8(uy.y), v2 = dec8(uy.z), v3 = dec8(uy.w);
    float s = v0 + v1 + v2 + v3;
    float s2 = v0 * v0 + v1 * v1 + v2 * v2 + v3 * v3;
    for (int off = 32; off; off >>= 1) {
        s  += __shfl_down(s,  off, 64);
        s2 += __shfl_down(s2, off, 64);
    }
    __shared__ float ps[4], ps2[4];
    __shared__ float smu, srstd;
    int wid = tid >> 6, lid = tid & 63;
    if (lid == 0) { ps[wid] = s; ps2[wid] = s2; }
    __syncthreads();
    if (tid == 0) {
        float t = ps[0] + ps[1] + ps[2] + ps[3];
        float t2 = ps2[0] + ps2[1] + ps2[2] + ps2[3];
        float m = t / D_;
        float var = t2 / D_ - m * m;
        smu = m; srstd = rsqrtf(var + 1e-5f);
    }
    __syncthreads();
    float mu = smu, rstd = srstd;
    float4 gv = *(const float4*)&g[tid * 4];
    float4 bv = *(const float4*)&bb[tid * 4];
    float4 scv = *(const float4*)&embo[b * 2048 + tid * 4];
    float4 shv = *(const float4*)&embo[b * 2048 + 1024 + tid * 4];
    float n0 = (v0 - mu) * rstd * gv.x + bv.x;
    float n1 = (v1 - mu) * rstd * gv.y + bv.y;
    float n2 = (v2 - mu) * rstd * gv.z + bv.z;
    float n3 = (v3 - mu) * rstd * gv.w + bv.w;
    float h0 = n0 * (1.f + scv.x) + shv.x;
    float h1 = n1 * (1.f + scv.y) + shv.y;
    float h2 = n2 * (1.f + scv.z) + shv.z;
    float h3 = n3 * (1.f + scv.w) + shv.w;
    h0 = h0 / (1.f + __expf(-h0));
    h1 = h1 / (1.f + __expf(-h1));
    h2 = h2 / (1.f + __expf(-h2));
    h3 = h3 / (1.f + __expf(-h3));
    *(int*)&a8[(size_t)row * D_ + tid * 4] = pk4_fp8(h0, h1, h2, h3);
}

extern "C" void kernel_launch(void* const* d_in, const int* in_sizes, int n_in,
                              void* d_out, int out_size, void* d_ws, size_t ws_size,
                              hipStream_t stream) {
    const float* x    = (const float*)d_in[0];
    const float* xf   = (const float*)d_in[1];
    const float* emb  = (const float*)d_in[2];
    const float* ln_g = (const float*)d_in[3];
    const float* ln_b = (const float*)d_in[4];
    const float* cln_g= (const float*)d_in[5];
    const float* cln_b= (const float*)d_in[6];
    const float* Wq   = (const float*)d_in[7];
    const float* bq   = (const float*)d_in[8];
    const float* Wk   = (const float*)d_in[9];
    const float* bk   = (const float*)d_in[10];
    const float* Wv   = (const float*)d_in[11];
    const float* bv   = (const float*)d_in[12];
    const float* sln_g= (const float*)d_in[13];
    const float* sln_b= (const float*)d_in[14];
    const float* Wemb = (const float*)d_in[15];
    const float* bemb = (const float*)d_in[16];
    const float* Wout = (const float*)d_in[17];
    const float* bout = (const float*)d_in[18];
    float* out = (float*)d_out;

    char* wsp = (char*)d_ws;
    const size_t MB = 1024 * 1024;
    uchar* xn8  = (uchar*)(wsp);                  // 8192x1024 fp8   8 MB
    uchar* xfn8 = (uchar*)(wsp + 8 * MB);         // 2048x768  fp8  1.5 MB
    uchar* wq8  = (uchar*)(wsp + 10 * MB);        // 1024x1024 fp8   1 MB
    uchar* wk8  = (uchar*)(wsp + 11 * MB);        //                .75 MB
    uchar* wv8  = (uchar*)(wsp + 12 * MB);        //                .75 MB
    uchar* wo8  = (uchar*)(wsp + 13 * MB);        //                 1 MB
    uchar* q8   = (uchar*)(wsp + 14 * MB);        // 8192x1024 fp8   8 MB
    uchar* k8   = (uchar*)(wsp + 22 * MB);        // 2048x1024 fp8   2 MB
    uchar* vT8  = (uchar*)(wsp + 24 * MB);        // pre-swizzled    2 MB
    uchar* y8   = (uchar*)(wsp + 26 * MB);        // 8192x1024 fp8   8 MB
    uchar* a8   = (uchar*)(wsp + 34 * MB);        // 8192x1024 fp8   8 MB
    float* embo = (float*)(wsp + 42 * MB);        // 8x2048    f32  64 KB
    float* part = (float*)(wsp + 43 * MB);        // 8x8x2048  f32  512 KB

    prep_kernel<<<11392, 256, 0, stream>>>(x, xf, ln_g, ln_b, cln_g, cln_b,
                                           Wq, Wk, Wv, Wout, emb, Wemb,
                                           xn8, xfn8, wq8, wk8, wv8, wo8, part);

    qkv_gemm<<<1600, 256, 0, stream>>>(xn8, xfn8, wq8, wk8, wv8, bq, bk, bv,
                                       q8, k8, vT8, part, bemb, embo);

    attn_mfma<<<dim3(16, 128), 256, 0, stream>>>(q8, k8, vT8, y8);

    styl_kernel<<<B_ * T_, 256, 0, stream>>>(y8, sln_g, sln_b, embo, a8);

    out_gemm<<<1024, 256, 0, stream>>>(a8, wo8, bout, x, out);
}